// Round 4
// baseline (49.173 us; speedup 1.0000x reference)
//
#include <hip/hip_runtime.h>
#include <hip/hip_bf16.h>

// B=8, N=2048, H=256, HEADS=4, hd=64, BNECK=8 (TB=24, 3H=768)
// attn_reg_loss = exp(log_w)/N exactly (softmax rows sum to 1) -> gu/gv dead.
// WvA-trick: vA[n][h,g] = t1[n]@WvA_h + bvA_h (WvA_h = Wv_h@Wo1_h, [24][8]);
// A_h[d][g] = sum_n kf[n][h*64+d]*vA[n][h,g]; out = ((z*qf)@A)@Wo2 + bias.
//
// ws (floats): t1 [16384][24] @0; z [8][4][2048] @393216;
//              Ap [512][2048] @458752; A [8][2048] @1507328.

#define OFF_T1  0
#define OFF_Z   393216
#define OFF_AP  458752
#define OFF_A   1507328

// ---------------------------------------------------------------------------
// F1: fused t1 -> (kf, vA, z, A-partials). 256 blocks x 512 threads, 64 rows.
// t1: K-split, slice = wave id (readfirstlane) -> Wq1 via scalar loads;
//     x global->reg; cross-slice reduce via t1p LDS.
// kf: thread c generates AND consumes kf[n][c] (register only, no LDS);
//     z via 64-lane shfl reduce (wave == head); A-acc 8 regs/thread.
// ---------------------------------------------------------------------------
__global__ __launch_bounds__(512) void f1_t1kva(
    const float* __restrict__ x, const float* __restrict__ Wq1,
    const float* __restrict__ bq1, const float* __restrict__ Wq2,
    const float* __restrict__ bq2, const float* __restrict__ Wo1,
    const float* __restrict__ logw,
    float* __restrict__ t1g, float* __restrict__ Ap,
    float* __restrict__ zg, float* __restrict__ loss_out)
{
    __shared__ float t1p[8][64][24];   // 49.2 KB; aliased by vas after reduce
    __shared__ float t1s[64][24];      // 6 KB
    __shared__ float wvas[25][32];     // [j][h*8+g]; row 24 = bvA
    float* vas = &t1p[0][0][0];        // [64][36] alias (2304 w <= 12288 w)

    const int t = threadIdx.x;
    const int bi = blockIdx.x;
    const long row0 = (long)bi * 64;
    const int b = bi >> 5;
    const int r = t & 63;
    const int sw = __builtin_amdgcn_readfirstlane(t >> 6);   // k-slice = wave

    // ---- t1 partials over k in [sw*32, sw*32+32)
    float x32[32];
    {
        const float* xrow = x + (row0 + r) * 256 + sw * 32;
        #pragma unroll
        for (int i = 0; i < 8; ++i) {
            const float4 v4 = *reinterpret_cast<const float4*>(xrow + i * 4);
            x32[i*4+0] = v4.x; x32[i*4+1] = v4.y;
            x32[i*4+2] = v4.z; x32[i*4+3] = v4.w;
        }
    }
    {
        float acc[24] = {};
        const float* wbase = Wq1 + sw * 768;   // uniform -> s_load
        #pragma unroll
        for (int ki = 0; ki < 32; ++ki) {
            #pragma unroll
            for (int j4 = 0; j4 < 6; ++j4) {
                const float4 wv = *reinterpret_cast<const float4*>(wbase + ki*24 + j4*4);
                acc[j4*4+0] = fmaf(x32[ki], wv.x, acc[j4*4+0]);
                acc[j4*4+1] = fmaf(x32[ki], wv.y, acc[j4*4+1]);
                acc[j4*4+2] = fmaf(x32[ki], wv.z, acc[j4*4+2]);
                acc[j4*4+3] = fmaf(x32[ki], wv.w, acc[j4*4+3]);
            }
        }
        #pragma unroll
        for (int j4 = 0; j4 < 6; ++j4)
            *reinterpret_cast<float4*>(&t1p[t>>6][r][j4*4]) =
                make_float4(acc[j4*4+0], acc[j4*4+1], acc[j4*4+2], acc[j4*4+3]);
    }
    __syncthreads();

    // ---- reduce 8 slices + bias; write t1s and t1g (coalesced b32)
    #pragma unroll
    for (int p = 0; p < 3; ++p) {
        const int o = t + p * 512;          // 0..1535
        const int rr = o / 24, jj = o - rr * 24;
        float s = 0.f;
        #pragma unroll
        for (int sl = 0; sl < 8; ++sl) s += t1p[sl][rr][jj];
        s += bq1[jj];
        t1s[rr][jj] = s;
        t1g[row0 * 24 + o] = s;
    }
    // ---- WvA = Wv_h @ Wo1_h (+ bvA) into LDS (weights-only, tiny)
    #pragma unroll
    for (int pass = 0; pass < 2; ++pass) {
        const int o = t + pass * 512;
        if (o < 768) {
            const int j = o >> 5, hg = o & 31, h = hg >> 3, g = hg & 7;
            const float* wv2 = Wq2 + j * 768 + 512 + h * 64;
            const float* wo  = Wo1 + (h * 64) * 8 + g;
            float s = 0.f;
            #pragma unroll 16
            for (int e = 0; e < 64; ++e) s = fmaf(wv2[e], wo[e * 8], s);
            wvas[j][hg] = s;
        } else if (o < 800) {
            const int hg = o & 31, h = hg >> 3, g = hg & 7;
            const float* bv = bq2 + 512 + h * 64;
            const float* wo = Wo1 + (h * 64) * 8 + g;
            float s = 0.f;
            #pragma unroll 16
            for (int e = 0; e < 64; ++e) s = fmaf(bv[e], wo[e * 8], s);
            wvas[24][hg] = s;
        }
    }
    if (bi == 0 && t == 0) loss_out[0] = __expf(logw[0]) * (1.0f / 2048.0f);
    __syncthreads();

    // ---- vA[n][hg] = t1s[n]@wvas[:,hg] + bvA  (stride 36, 16B-aligned)
    {
        const int hg = t & 31, n0 = t >> 5;   // n0 0..15
        float wva[24];
        #pragma unroll
        for (int j = 0; j < 24; ++j) wva[j] = wvas[j][hg];
        const float bva = wvas[24][hg];
        #pragma unroll
        for (int p = 0; p < 4; ++p) {
            const int n = n0 + p * 16;
            float s = bva;
            #pragma unroll
            for (int j4 = 0; j4 < 24; j4 += 4) {
                const float4 tv = *reinterpret_cast<const float4*>(&t1s[n][j4]);
                s = fmaf(tv.x, wva[j4+0], s);
                s = fmaf(tv.y, wva[j4+1], s);
                s = fmaf(tv.z, wva[j4+2], s);
                s = fmaf(tv.w, wva[j4+3], s);
            }
            vas[n * 36 + hg] = s;
        }
    }
    __syncthreads();

    // ---- fused kf-gen + z + A-acc (kf never touches LDS)
    {
        const int c = t & 255;
        const int chalf = t >> 8;            // row half
        const int h = c >> 6;                // == wave's head
        const int lane = t & 63;
        float wk[24];
        #pragma unroll
        for (int j = 0; j < 24; ++j) wk[j] = Wq2[j * 768 + 256 + c];
        const float bk = bq2[256 + c];
        float accA[8] = {};
        const long zb = (((long)b * 4 + h) << 11) + (row0 & 2047);
        #pragma unroll 4
        for (int nn = 0; nn < 32; ++nn) {
            const int n = chalf * 32 + nn;
            float sk = bk;
            #pragma unroll
            for (int j4 = 0; j4 < 24; j4 += 4) {
                const float4 tv = *reinterpret_cast<const float4*>(&t1s[n][j4]);
                sk = fmaf(tv.x, wk[j4+0], sk);
                sk = fmaf(tv.y, wk[j4+1], sk);
                sk = fmaf(tv.z, wk[j4+2], sk);
                sk = fmaf(tv.w, wk[j4+3], sk);
            }
            const float kf = sk > 0.f ? sk + 1.f : __expf(sk);
            // z: sum kf over the wave's 64 lanes (= this head's 64 dims)
            float zs = kf;
            zs += __shfl_xor(zs, 1, 64);
            zs += __shfl_xor(zs, 2, 64);
            zs += __shfl_xor(zs, 4, 64);
            zs += __shfl_xor(zs, 8, 64);
            zs += __shfl_xor(zs, 16, 64);
            zs += __shfl_xor(zs, 32, 64);
            if (lane == 0) zg[zb + n] = 1.0f / (zs + 1e-8f);
            // A-acc
            const float4 va0 = *reinterpret_cast<const float4*>(&vas[n*36 + h*8]);
            const float4 va1 = *reinterpret_cast<const float4*>(&vas[n*36 + h*8 + 4]);
            accA[0] = fmaf(kf, va0.x, accA[0]); accA[1] = fmaf(kf, va0.y, accA[1]);
            accA[2] = fmaf(kf, va0.z, accA[2]); accA[3] = fmaf(kf, va0.w, accA[3]);
            accA[4] = fmaf(kf, va1.x, accA[4]); accA[5] = fmaf(kf, va1.y, accA[5]);
            accA[6] = fmaf(kf, va1.w ? va1.z : va1.z, accA[6]); accA[7] = fmaf(kf, va1.w, accA[7]);
        }
        float* dst = Ap + ((long)bi * 2 + chalf) * 2048 + c * 8;
        *reinterpret_cast<float4*>(dst)     = make_float4(accA[0], accA[1], accA[2], accA[3]);
        *reinterpret_cast<float4*>(dst + 4) = make_float4(accA[4], accA[5], accA[6], accA[7]);
    }
}

// ---------------------------------------------------------------------------
// K2b: A[b][idx] = sum over 64 chunk-partials. 256 blocks x 256 threads,
// split-j x4 with tiny LDS combine.
// ---------------------------------------------------------------------------
__global__ __launch_bounds__(256) void k2b_redA(
    const float* __restrict__ Ap, float* __restrict__ Ag)
{
    __shared__ float red[4][64];
    const int bid = blockIdx.x;           // 8b x 32seg
    const int b = bid >> 5, seg = bid & 31;
    const int t = threadIdx.x;
    const int l = t & 63, jq = t >> 6;
    const int idx = seg * 64 + l;
    const float* src = Ap + ((long)b * 64 + jq * 16) * 2048 + idx;
    float s = 0.f;
    #pragma unroll
    for (int j = 0; j < 16; ++j) s += src[(long)j * 2048];
    red[jq][l] = s;
    __syncthreads();
    if (t < 64)
        Ag[(long)b * 2048 + idx] =
            (red[0][t] + red[1][t]) + (red[2][t] + red[3][t]);
}

// ---------------------------------------------------------------------------
// K3: out = ((z*qf)@A)@Wo2 + bias. 1024 blocks x 256 threads, 16 rows.
// P1 thread=c (qf regen, Wq2 col in regs); P2 split-K rank-8 GEMM with
// conflict-free pads (zqf stride 258: 2-way; AsT broadcast); P3 coalesced.
// ---------------------------------------------------------------------------
__global__ __launch_bounds__(256) void k3_out(
    const float* __restrict__ t1g, const float* __restrict__ Wq2,
    const float* __restrict__ bq2, const float* __restrict__ zg,
    const float* __restrict__ Ag,
    const float* __restrict__ bo1, const float* __restrict__ Wo2,
    const float* __restrict__ bo2, float* __restrict__ outg)
{
    __shared__ __align__(16) float t1s[384];       // [16][24]
    __shared__ __align__(16) float zqf[16 * 258];
    __shared__ __align__(16) float AsT[8 * 264];   // [g][h*64+d]
    __shared__ float o1p[2][16][8];
    __shared__ __align__(16) float o1s[16][8];
    const int t = threadIdx.x;
    const int bid = blockIdx.x;
    const long row0 = (long)bid * 16;
    const int b = bid >> 7;

    if (t < 96) {
        const float4 v4 = *reinterpret_cast<const float4*>(&t1g[row0 * 24 + t * 4]);
        *reinterpret_cast<float4*>(&t1s[t * 4]) = v4;
    }
    #pragma unroll
    for (int kk = 0; kk < 8; ++kk) {
        const int o = kk * 256 + t;                 // h*512 + d*8 + g
        AsT[(o & 7) * 264 + (o >> 3)] = Ag[(long)b * 2048 + o];
    }
    float wq[24];
    #pragma unroll
    for (int j = 0; j < 24; ++j) wq[j] = Wq2[j * 768 + t];
    const float bqc = bq2[t];
    float wo2r[8];
    #pragma unroll
    for (int j = 0; j < 8; ++j) wo2r[j] = Wo2[j * 256 + t];
    const float bo2e = bo2[t];
    const int h1 = t >> 6;
    const long zb = (((long)b * 4 + h1) << 11) + (row0 & 2047);
    __syncthreads();

    // P1: zqf
    #pragma unroll 4
    for (int r = 0; r < 16; ++r) {
        float q0 = bqc;
        #pragma unroll
        for (int j4 = 0; j4 < 24; j4 += 4) {
            const float4 tv = *reinterpret_cast<const float4*>(&t1s[r * 24 + j4]);
            q0 = fmaf(tv.x, wq[j4+0], q0);
            q0 = fmaf(tv.y, wq[j4+1], q0);
            q0 = fmaf(tv.z, wq[j4+2], q0);
            q0 = fmaf(tv.w, wq[j4+3], q0);
        }
        const float qf = q0 > 0.f ? q0 + 1.f : __expf(q0);
        zqf[r * 258 + t] = qf * zg[zb + r];
    }
    __syncthreads();

    // P2: o1[r][g] = sum_c zqf[r][c]*AsT[g][c], split-K over 2 halves
    {
        const int g = t >> 5, u = t & 31;
        const int r = u & 15, ch2 = u >> 4;
        const float* zrow = &zqf[r * 258 + ch2 * 128];
        const float* arow = &AsT[g * 264 + ch2 * 128];
        float s = 0.f;
        #pragma unroll 16
        for (int i = 0; i < 128; i += 2) {
            const float2 zq = *reinterpret_cast<const float2*>(zrow + i);
            const float2 av = *reinterpret_cast<const float2*>(arow + i);
            s = fmaf(zq.x, av.x, s);
            s = fmaf(zq.y, av.y, s);
        }
        o1p[ch2][r][g] = s;
    }
    __syncthreads();
    if (t < 128) {
        const int r = t >> 3, g = t & 7;
        o1s[r][g] = o1p[0][r][g] + o1p[1][r][g] + bo1[g];
    }
    __syncthreads();

    // P3: out[row][e]
    #pragma unroll 4
    for (int r = 0; r < 16; ++r) {
        const float4 oa = *reinterpret_cast<const float4*>(&o1s[r][0]);
        const float4 ob = *reinterpret_cast<const float4*>(&o1s[r][4]);
        float vv = bo2e;
        vv = fmaf(oa.x, wo2r[0], vv); vv = fmaf(oa.y, wo2r[1], vv);
        vv = fmaf(oa.z, wo2r[2], vv); vv = fmaf(oa.w, wo2r[3], vv);
        vv = fmaf(ob.x, wo2r[4], vv); vv = fmaf(ob.y, wo2r[5], vv);
        vv = fmaf(ob.z, wo2r[6], vv); vv = fmaf(ob.w, wo2r[7], vv);
        outg[(row0 + r) * 256 + t] = vv;
    }
}

// ---------------------------------------------------------------------------
extern "C" void kernel_launch(void* const* d_in, const int* in_sizes, int n_in,
                              void* d_out, int out_size, void* d_ws, size_t ws_size,
                              hipStream_t stream)
{
    const float* x    = (const float*)d_in[0];
    const float* Wq1  = (const float*)d_in[1];
    const float* bq1  = (const float*)d_in[2];
    const float* Wq2  = (const float*)d_in[3];
    const float* bq2  = (const float*)d_in[4];
    const float* Wo1  = (const float*)d_in[5];
    const float* bo1  = (const float*)d_in[6];
    const float* Wo2  = (const float*)d_in[7];
    const float* bo2  = (const float*)d_in[8];
    // d_in[9] = gu, d_in[10] = gv : unused (reg-loss collapses analytically)
    const float* logw = (const float*)d_in[11];

    float* out = (float*)d_out;            // [8,2048,256] f32 + loss scalar
    float* ws  = (float*)d_ws;
    float* t1g = ws + OFF_T1;
    float* zg  = ws + OFF_Z;
    float* Apg = ws + OFF_AP;
    float* Agg = ws + OFF_A;

    f1_t1kva<<<256, 512, 0, stream>>>(x, Wq1, bq1, Wq2, bq2, Wo1, logw,
                                      t1g, Apg, zg, out + 4194304);
    k2b_redA<<<256, 256, 0, stream>>>(Apg, Agg);
    k3_out<<<1024, 256, 0, stream>>>(t1g, Wq2, bq2, zg, Agg,
                                     bo1, Wo2, bo2, out);
}